// Round 1
// baseline (209.087 us; speedup 1.0000x reference)
//
#include <hip/hip_runtime.h>
#include <hip/hip_bf16.h>

// Problem shapes (fixed by setup_inputs)
constexpr int B_  = 4;
constexpr int N_  = 2048;
constexpr int C_  = 1024;
constexpr int H_  = 16;
constexpr int HD  = 64;    // head dim
constexpr int LR  = 20;    // low rank
constexpr int RS  = 200;   // subsample length R
constexpr int RP  = 224;   // RS padded to multiple of 32 (zero-filled)

typedef __attribute__((ext_vector_type(8))) short bf16x8;
typedef __attribute__((ext_vector_type(4))) float f32x4;

__device__ __forceinline__ float b2f_raw(unsigned short u) {
    union { unsigned int i; float f; } v;
    v.i = ((unsigned int)u) << 16;
    return v.f;
}
__device__ __forceinline__ unsigned short f2b(float f) {
    __hip_bfloat16 h = __float2bfloat16(f);
    return *(unsigned short*)&h;
}
template <bool BF>
__device__ __forceinline__ float ldg(const void* p, size_t i) {
    if constexpr (BF) return b2f_raw(((const unsigned short*)p)[i]);
    else              return ((const float*)p)[i];
}

// async 16B global->LDS (wave-uniform LDS base; HW scatters lane i at +16*i)
__device__ __forceinline__ void async_load16(const unsigned short* g, unsigned short* l) {
    __builtin_amdgcn_global_load_lds(
        (const __attribute__((address_space(1))) unsigned int*)(const void*)g,
        (__attribute__((address_space(3))) unsigned int*)(void*)l,
        16, 0, 0);
}

// ---------------------------------------------------------------------------
// dtype detection (single tiny kernel — proven cheap in rounds 2-7).
// ---------------------------------------------------------------------------
__global__ __launch_bounds__(256)
void detect_kernel(const unsigned int* __restrict__ x, int* __restrict__ flag) {
    const int t = threadIdx.x;
    int cnt = 0;
    for (int i = t; i < 1024; i += 256) {
        const unsigned int w = x[i];
        const unsigned int e = (w >> 7) & 0xFFu;
        cnt += (e >= 103u && e <= 140u) ? 1 : 0;
    }
    __shared__ int s[256];
    s[t] = cnt;
    __syncthreads();
    for (int off = 128; off > 0; off >>= 1) {
        if (t < off) s[t] += s[t + off];
        __syncthreads();
    }
    if (t == 0) *flag = (s[0] > 512) ? 1 : 0;  // 1 = bf16 inputs, 0 = fp32
}

// ---------------------------------------------------------------------------
// Fused convert + wec + gather. Grid (2048, 7):
//  y in [0,5): convert buffer y (x, qkw, proj_w, proj_b, cw_b) to bf16
//  y == 5:    wec from RAW we/wr/cw_w: wect[h][dout][r] = sum_e we*cw
//  y == 6:    gather from RAW x: xh[bh][din][r] = x[b, idx[r], h*64+din]
// idx[r] = (r*(N-1))/(R-1) exactly (trunc linspace); r zero-padded to 224.
// ---------------------------------------------------------------------------
struct CvtArgs {
    const void* src[5];
    unsigned short* dst[5];
    int size[5];
};

template <bool BF>
__device__ void wec_body(const void* __restrict__ we_raw,
                         const void* __restrict__ wr_raw,
                         const void* __restrict__ cw_raw,
                         unsigned short* __restrict__ wect,
                         unsigned short* __restrict__ wrct) {
    const int o = blockIdx.x * 256 + threadIdx.x;
    if (o >= H_ * HD * RP) return;
    const int r    = o % RP;
    const int dout = (o / RP) % HD;
    const int h    = o / (RP * HD);
    float sq = 0.f, sk = 0.f;
    if (r < RS) {
        #pragma unroll
        for (int e = 0; e < LR; ++e) {
            const float cq = ldg<BF>(cw_raw, dout * 2 * LR + e);
            const float ck = ldg<BF>(cw_raw, dout * 2 * LR + LR + e);
            sq += ldg<BF>(we_raw, ((size_t)h * RS + r) * LR + e) * cq;
            sk += ldg<BF>(wr_raw, ((size_t)h * RS + r) * LR + e) * ck;
        }
    }
    wect[o] = f2b(sq);
    wrct[o] = f2b(sk);
}

template <bool BF>
__device__ void gather_body(const void* __restrict__ x_raw,
                            unsigned short* __restrict__ xh) {
    const int bh = blockIdx.x;
    if (bh >= B_ * H_) return;
    const int b = bh >> 4;
    const int h = bh & 15;
    for (int o = threadIdx.x; o < HD * RP; o += 256) {
        const int din = o & 63;   // consecutive threads -> coalesced reads
        const int r   = o >> 6;
        unsigned short v = 0;
        if (r < RS) {
            const int ir = (r * (N_ - 1)) / (RS - 1);
            const size_t idx = ((size_t)b * N_ + ir) * C_ + h * HD + din;
            if constexpr (BF) v = ((const unsigned short*)x_raw)[idx];
            else              v = f2b(((const float*)x_raw)[idx]);
        }
        xh[(size_t)bh * HD * RP + (size_t)din * RP + r] = v;
    }
}

__global__ __launch_bounds__(256)
void fused_prep_kernel(const int* __restrict__ flag, CvtArgs args,
                       const void* __restrict__ we_raw,
                       const void* __restrict__ wr_raw,
                       const void* __restrict__ cw_raw,
                       unsigned short* __restrict__ wect,
                       unsigned short* __restrict__ wrct,
                       unsigned short* __restrict__ xh) {
    const bool isbf = (*flag != 0);
    const int y = blockIdx.y;
    if (y < 5) {
        const int n4 = args.size[y] >> 2;
        const int stride = gridDim.x * blockDim.x;
        for (int i = blockIdx.x * blockDim.x + threadIdx.x; i < n4; i += stride) {
            ushort4 o;
            if (isbf) {
                o = ((const ushort4*)args.src[y])[i];
            } else {
                const float4 v = ((const float4*)args.src[y])[i];
                o.x = f2b(v.x); o.y = f2b(v.y); o.z = f2b(v.z); o.w = f2b(v.w);
            }
            ((ushort4*)args.dst[y])[i] = o;
        }
    } else if (y == 5) {
        if (isbf) wec_body<true>(we_raw, wr_raw, cw_raw, wect, wrct);
        else      wec_body<false>(we_raw, wr_raw, cw_raw, wect, wrct);
    } else {
        if (isbf) gather_body<true>(args.src[0], xh);
        else      gather_body<false>(args.src[0], xh);
    }
}

// ---------------------------------------------------------------------------
// collapse: We2T[bh][dout][din] = sum_r wec[h][dout][r] * xh[bh][din][r]
// Tiny NT MFMA GEMM, M=N=64, K=224. One wave per (bh, qk-sel, dout-half).
// (verified in rounds 5-8)
// ---------------------------------------------------------------------------
__global__ __launch_bounds__(64)
void collapse_kernel(const unsigned short* __restrict__ xh,
                     const unsigned short* __restrict__ wect,
                     const unsigned short* __restrict__ wrct,
                     unsigned short* __restrict__ we2t,
                     unsigned short* __restrict__ wr2t) {
    const int blk = blockIdx.x;
    const int bh  = blk >> 2;
    const int qk  = (blk >> 1) & 1;
    const int dh  = blk & 1;
    const int h   = bh & 15;
    const int lane = threadIdx.x;
    const int lq = lane >> 4;
    const int lm = lane & 15;

    const unsigned short* wsrc = (qk ? wrct : wect) + (size_t)h * HD * RP;
    const unsigned short* xsrc = xh + (size_t)bh * HD * RP;
    unsigned short* dst = (qk ? wr2t : we2t) + (size_t)bh * HD * HD;

    f32x4 acc[2][4];
    #pragma unroll
    for (int i = 0; i < 2; ++i)
        #pragma unroll
        for (int j = 0; j < 4; ++j) acc[i][j] = 0.f;

    for (int ks = 0; ks < RP / 32; ++ks) {
        bf16x8 a[2], bfr[4];
        #pragma unroll
        for (int rt = 0; rt < 2; ++rt)
            a[rt] = *(const bf16x8*)&wsrc[(size_t)(dh * 32 + rt * 16 + lm) * RP + ks * 32 + lq * 8];
        #pragma unroll
        for (int j = 0; j < 4; ++j)
            bfr[j] = *(const bf16x8*)&xsrc[(size_t)(j * 16 + lm) * RP + ks * 32 + lq * 8];
        #pragma unroll
        for (int rt = 0; rt < 2; ++rt)
            #pragma unroll
            for (int j = 0; j < 4; ++j)
                acc[rt][j] = __builtin_amdgcn_mfma_f32_16x16x32_bf16(
                    a[rt], bfr[j], acc[rt][j], 0, 0, 0);
    }

    #pragma unroll
    for (int rt = 0; rt < 2; ++rt)
        #pragma unroll
        for (int j = 0; j < 4; ++j)
            #pragma unroll
            for (int r = 0; r < 4; ++r) {
                const int dout = dh * 32 + rt * 16 + lq * 4 + r;
                const int din  = j * 16 + lm;
                dst[dout * HD + din] = f2b(acc[rt][j][r]);
            }
}

// ---------------------------------------------------------------------------
// Fused gemm1 + l2norm + score.
// Phase 1 NEW (this round): BK=32 double-buffered prefetch pipeline
// (T3-minimum recipe: stage next tile BEFORE compute, ONE barrier/iter whose
// implicit vmcnt(0)+lgkmcnt(0) drain is exactly the recipe's requirement)
// + T2 XOR swizzle of the LDS tiles, applied both-sides-or-neither:
// global_load_lds keeps a LINEAR LDS destination; the per-lane GLOBAL source
// column-unit is pre-swizzled u^=((srow>>1)&3) (permutation within a 64B row,
// coalescing unchanged), and the ds_read column is (lq^((lm>>1)&3))*8 — a
// per-lane constant, so the hot loop gains zero VALU. This makes each 8-lane
// batch of ds_read_b128 cover all 32 banks (was 4-way aliased).
// ---------------------------------------------------------------------------
__global__ __launch_bounds__(256, 4)
void gemm1_score_kernel(const unsigned short* __restrict__ xb,
                        const unsigned short* __restrict__ qkwb,
                        const unsigned short* __restrict__ we2t,
                        const unsigned short* __restrict__ wr2t,
                        const unsigned short* __restrict__ cwbb,
                        unsigned short* __restrict__ attn) {
    constexpr int QS = 72;
    __shared__ __align__(16) unsigned short pool[2 * 128 * QS];  // 36 KB
    unsigned short* As0 = pool;                 // 128x32 (buffer 0, A)
    unsigned short* As1 = pool + 4096;          // 128x32 (buffer 1, A)
    unsigned short* Bs0 = pool + 8192;
    unsigned short* Bs1 = pool + 12288;
    unsigned short* qn  = pool;                 // phase 2: 128xQS
    unsigned short* kn  = pool + 128 * QS;

    const int t    = threadIdx.x;
    const int wave = t >> 6;
    const int lane = t & 63;
    const int h    = blockIdx.x;
    const int m0   = blockIdx.y * 128;
    const int K    = C_;

    const int srow = lane >> 2;
    // swizzled source column unit (inverse swizzle == swizzle; involution)
    const int scol = ((lane & 3) ^ ((srow >> 1) & 3)) * 8;
    const unsigned short* ga0 = xb + (size_t)(m0 + wave * 16 + srow) * K + scol;
    const unsigned short* ga1 = ga0 + (size_t)64 * K;
    const unsigned short* gb0 = qkwb + (size_t)(h * HD + wave * 16 + srow) * K + scol;
    const unsigned short* gb1 = gb0 + (size_t)C_ * K;

    const int wr = (wave >> 1) * 64;        // row quadrant
    const int wc = (wave & 1) * 64;         // col quadrant: 0 = q, 64 = k
    const int lq = lane >> 4;
    const int lm = lane & 15;
    const int cx = (lq ^ ((lm >> 1) & 3)) * 8;   // swizzled read column

    f32x4 acc[4][4];
    #pragma unroll
    for (int i = 0; i < 4; ++i)
        #pragma unroll
        for (int j = 0; j < 4; ++j) acc[i][j] = 0.f;

    auto stage = [&](unsigned short* dA, unsigned short* dB) {
        async_load16(ga0, dA + wave * 512);
        async_load16(ga1, dA + (wave + 4) * 512);
        async_load16(gb0, dB + wave * 512);
        async_load16(gb1, dB + (wave + 4) * 512);
        ga0 += 32; ga1 += 32; gb0 += 32; gb1 += 32;
    };
    auto compute = [&](const unsigned short* As, const unsigned short* Bs) {
        bf16x8 af[4], bfr[4];
        #pragma unroll
        for (int i = 0; i < 4; ++i)
            af[i] = *(const bf16x8*)&As[(wr + i * 16 + lm) * 32 + cx];
        #pragma unroll
        for (int j = 0; j < 4; ++j)
            bfr[j] = *(const bf16x8*)&Bs[(wc + j * 16 + lm) * 32 + cx];
        #pragma unroll
        for (int i = 0; i < 4; ++i)
            #pragma unroll
            for (int j = 0; j < 4; ++j)
                acc[i][j] = __builtin_amdgcn_mfma_f32_16x16x32_bf16(
                    af[i], bfr[j], acc[i][j], 0, 0, 0);
    };

    constexpr int NT = C_ / 32;    // 32 K-tiles
    stage(As0, Bs0);               // tile 0
    __syncthreads();
    for (int kt = 0; kt < NT - 2; kt += 2) {
        stage(As1, Bs1);           // tile kt+1 (issued before compute -> overlap)
        compute(As0, Bs0);         // tile kt
        __syncthreads();           // vmcnt(0)+lgkmcnt(0)+barrier: next tile landed,
        stage(As0, Bs0);           //   all reads of the overwritten buffer done
        compute(As1, Bs1);
        __syncthreads();
    }
    stage(As1, Bs1);               // tile NT-1
    compute(As0, Bs0);             // tile NT-2
    __syncthreads();
    compute(As1, Bs1);             // tile NT-1
    __syncthreads();               // before pool reuse by phase 2

    // ---- phase 2a: per-row l2 norm + scaled bf16 store to LDS ----
    unsigned short* dst = (wc == 0) ? qn : kn;
    #pragma unroll
    for (int i = 0; i < 4; ++i) {
        float inv[4];
        #pragma unroll
        for (int r = 0; r < 4; ++r) {
            float s = 0.f;
            #pragma unroll
            for (int j = 0; j < 4; ++j) s += acc[i][j][r] * acc[i][j][r];
            s += __shfl_xor(s, 1, 64);
            s += __shfl_xor(s, 2, 64);
            s += __shfl_xor(s, 4, 64);
            s += __shfl_xor(s, 8, 64);
            inv[r] = 1.f / fmaxf(sqrtf(s), 1e-12f);
        }
        #pragma unroll
        for (int j = 0; j < 4; ++j)
            #pragma unroll
            for (int r = 0; r < 4; ++r) {
                const int row = wr + i * 16 + lq * 4 + r;
                dst[row * QS + j * 16 + lm] = f2b(acc[i][j][r] * inv[r]);
            }
    }
    __syncthreads();

    // ---- phase 2b: attn = qn@We2T^T + kn@Wr2T^T + cw_b ----
    const int b  = blockIdx.y >> 4;
    const int bh = b * H_ + h;
    const unsigned short* wq = we2t + (size_t)bh * HD * HD;
    const unsigned short* wk = wr2t + (size_t)bh * HD * HD;

    bf16x8 bq[2][4], bk[2][4];
    #pragma unroll
    for (int t2 = 0; t2 < 2; ++t2)
        #pragma unroll
        for (int j = 0; j < 4; ++j) {
            const int dout = j * 16 + lm;
            bq[t2][j] = *(const bf16x8*)&wq[dout * HD + t2 * 32 + lq * 8];
            bk[t2][j] = *(const bf16x8*)&wk[dout * HD + t2 * 32 + lq * 8];
        }

    f32x4 accS[2][4];
    #pragma unroll
    for (int rt = 0; rt < 2; ++rt)
        #pragma unroll
        for (int j = 0; j < 4; ++j) accS[rt][j] = 0.f;

    #pragma unroll
    for (int rt = 0; rt < 2; ++rt) {
        const int lr = wave * 32 + rt * 16 + lm;
        bf16x8 aq0 = *(const bf16x8*)&qn[lr * QS + lq * 8];
        bf16x8 aq1 = *(const bf16x8*)&qn[lr * QS + 32 + lq * 8];
        bf16x8 ak0 = *(const bf16x8*)&kn[lr * QS + lq * 8];
        bf16x8 ak1 = *(const bf16x8*)&kn[lr * QS + 32 + lq * 8];
        #pragma unroll
        for (int j = 0; j < 4; ++j) {
            accS[rt][j] = __builtin_amdgcn_mfma_f32_16x16x32_bf16(aq0, bq[0][j], accS[rt][j], 0, 0, 0);
            accS[rt][j] = __builtin_amdgcn_mfma_f32_16x16x32_bf16(aq1, bq[1][j], accS[rt][j], 0, 0, 0);
            accS[rt][j] = __builtin_amdgcn_mfma_f32_16x16x32_bf16(ak0, bk[0][j], accS[rt][j], 0, 0, 0);
            accS[rt][j] = __builtin_amdgcn_mfma_f32_16x16x32_bf16(ak1, bk[1][j], accS[rt][j], 0, 0, 0);
        }
    }

    #pragma unroll
    for (int rt = 0; rt < 2; ++rt)
        #pragma unroll
        for (int j = 0; j < 4; ++j) {
            const int dout = j * 16 + lm;
            const float bv = b2f_raw(cwbb[dout]);
            #pragma unroll
            for (int r = 0; r < 4; ++r) {
                const int row = m0 + wave * 32 + rt * 16 + lq * 4 + r;
                attn[(size_t)row * C_ + h * HD + dout] = f2b(accS[rt][j][r] + bv);
            }
        }
}

// ---------------------------------------------------------------------------
// Output projection: same BK=32 double-buffered prefetch + swizzle body.
// Flag selects output dtype.
// ---------------------------------------------------------------------------
template <bool OBF>
__device__ void mfma_gemm_body32(const unsigned short* __restrict__ A,
                                 const unsigned short* __restrict__ W,
                                 const unsigned short* __restrict__ bias,
                                 void* __restrict__ out,
                                 int M, int N, int K) {
    __shared__ __align__(16) unsigned short As0[4096], As1[4096];
    __shared__ __align__(16) unsigned short Bs0[4096], Bs1[4096];   // 32 KB

    const int t    = threadIdx.x;
    const int wave = t >> 6;
    const int lane = t & 63;
    const int m0   = blockIdx.y * 128;
    const int n0   = blockIdx.x * 128;

    const int srow = lane >> 2;
    const int scol = ((lane & 3) ^ ((srow >> 1) & 3)) * 8;  // swizzled source
    const unsigned short* ga0 = A + (size_t)(m0 + wave * 16 + srow) * K + scol;
    const unsigned short* ga1 = ga0 + (size_t)64 * K;
    const unsigned short* gb0 = W + (size_t)(n0 + wave * 16 + srow) * K + scol;
    const unsigned short* gb1 = gb0 + (size_t)64 * K;

    const int wr = (wave >> 1) * 64;
    const int wc = (wave & 1) * 64;
    const int lq = lane >> 4;
    const int lm = lane & 15;
    const int cx = (lq ^ ((lm >> 1) & 3)) * 8;   // swizzled read column

    f32x4 acc[4][4];
    #pragma unroll
    for (int i = 0; i < 4; ++i)
        #pragma unroll
        for (int j = 0; j < 4; ++j) acc[i][j] = 0.f;

    auto stage = [&](unsigned short* dA, unsigned short* dB) {
        async_load16(ga0, dA + wave * 512);
        async_load16(ga1, dA + (wave + 4) * 512);
        async_load16(gb0, dB + wave * 512);
        async_load16(gb1, dB + (wave + 4) * 512);
        ga0 += 32; ga1 += 32; gb0 += 32; gb1 += 32;
    };
    auto compute = [&](const unsigned short* As, const unsigned short* Bs) {
        bf16x8 af[4], bfr[4];
        #pragma unroll
        for (int i = 0; i < 4; ++i)
            af[i] = *(const bf16x8*)&As[(wr + i * 16 + lm) * 32 + cx];
        #pragma unroll
        for (int j = 0; j < 4; ++j)
            bfr[j] = *(const bf16x8*)&Bs[(wc + j * 16 + lm) * 32 + cx];
        #pragma unroll
        for (int i = 0; i < 4; ++i)
            #pragma unroll
            for (int j = 0; j < 4; ++j)
                acc[i][j] = __builtin_amdgcn_mfma_f32_16x16x32_bf16(
                    af[i], bfr[j], acc[i][j], 0, 0, 0);
    };

    const int NT = K / 32;
    stage(As0, Bs0);
    __syncthreads();
    for (int kt = 0; kt < NT - 2; kt += 2) {
        stage(As1, Bs1);
        compute(As0, Bs0);
        __syncthreads();
        stage(As0, Bs0);
        compute(As1, Bs1);
        __syncthreads();
    }
    stage(As1, Bs1);
    compute(As0, Bs0);
    __syncthreads();
    compute(As1, Bs1);
    // epilogue is register-only: no trailing barrier needed

    #pragma unroll
    for (int i = 0; i < 4; ++i) {
        #pragma unroll
        for (int j = 0; j < 4; ++j) {
            const int col = n0 + wc + j * 16 + lm;
            const float bv = b2f_raw(bias[col]);
            #pragma unroll
            for (int r = 0; r < 4; ++r) {
                const int row = m0 + wr + i * 16 + lq * 4 + r;
                const float v = acc[i][j][r] + bv;
                if constexpr (OBF)
                    ((__hip_bfloat16*)out)[(size_t)row * N + col] = __float2bfloat16(v);
                else
                    ((float*)out)[(size_t)row * N + col] = v;
            }
        }
    }
}

__global__ __launch_bounds__(256, 4)
void gemm2_kernel(const int* __restrict__ flag,
                  const unsigned short* __restrict__ attn,
                  const unsigned short* __restrict__ pwb,
                  const unsigned short* __restrict__ pbb,
                  void* __restrict__ out) {
    if (*flag) mfma_gemm_body32<true>(attn, pwb, pbb, out, B_ * N_, C_, C_);
    else       mfma_gemm_body32<false>(attn, pwb, pbb, out, B_ * N_, C_, C_);
}

// ---------------------------------------------------------------------------
// 5 dispatches: detect -> fused(convert+wec+gather) -> collapse ->
// gemm1_score -> gemm2. ws high-water ~44 MB (< proven-safe 57.9 MB).
// ---------------------------------------------------------------------------
extern "C" void kernel_launch(void* const* d_in, const int* in_sizes, int n_in,
                              void* d_out, int out_size, void* d_ws, size_t ws_size,
                              hipStream_t stream) {
    (void)in_sizes; (void)n_in; (void)out_size; (void)ws_size;

    char* ws = (char*)d_ws;
    size_t off = 0;
    auto alloc = [&](size_t bytes) {
        char* p = ws + off;
        off += (bytes + 255) & ~(size_t)255;
        return p;
    };

    int* flag = (int*)alloc(16);
    unsigned short* xb    = (unsigned short*)alloc((size_t)B_ * N_ * C_ * 2);   // 16.78 MB
    unsigned short* qkwb  = (unsigned short*)alloc((size_t)2 * C_ * C_ * 2);    // 4.19 MB
    unsigned short* pwb   = (unsigned short*)alloc((size_t)C_ * C_ * 2);        // 2.10 MB
    unsigned short* pbb   = (unsigned short*)alloc((size_t)C_ * 2);
    unsigned short* cwbb  = (unsigned short*)alloc((size_t)HD * 2);
    unsigned short* attn  = (unsigned short*)alloc((size_t)B_ * N_ * C_ * 2);   // 16.78 MB
    unsigned short* we2t  = (unsigned short*)alloc((size_t)B_ * H_ * HD * HD * 2);
    unsigned short* wr2t  = (unsigned short*)alloc((size_t)B_ * H_ * HD * HD * 2);
    unsigned short* wect  = (unsigned short*)alloc((size_t)H_ * HD * RP * 2);
    unsigned short* wrct  = (unsigned short*)alloc((size_t)H_ * HD * RP * 2);
    unsigned short* xh    = (unsigned short*)alloc((size_t)B_ * H_ * HD * RP * 2);

    const int M = B_ * N_;  // 8192

    // 1) dtype detection
    detect_kernel<<<1, 256, 0, stream>>>((const unsigned int*)d_in[0], flag);

    // 2) fused convert (x, qk_w, proj_w, proj_b, cw_b) + wec + gather
    CvtArgs ca;
    ca.src[0] = d_in[0]; ca.dst[0] = xb;   ca.size[0] = B_ * N_ * C_;
    ca.src[1] = d_in[1]; ca.dst[1] = qkwb; ca.size[1] = 2 * C_ * C_;
    ca.src[2] = d_in[2]; ca.dst[2] = pwb;  ca.size[2] = C_ * C_;
    ca.src[3] = d_in[3]; ca.dst[3] = pbb;  ca.size[3] = C_;
    ca.src[4] = d_in[7]; ca.dst[4] = cwbb; ca.size[4] = HD;
    fused_prep_kernel<<<dim3(2048, 7), 256, 0, stream>>>(
        flag, ca, d_in[4], d_in[5], d_in[6], wect, wrct, xh);

    // 3) collapse -> We2T/Wr2T
    collapse_kernel<<<B_ * H_ * 4, 64, 0, stream>>>(xh, wect, wrct, we2t, wr2t);

    // 4) fused qk-projection + l2norm + score -> attn
    gemm1_score_kernel<<<dim3(H_, M / 128), 256, 0, stream>>>(
        xb, qkwb, we2t, wr2t, cwbb, attn);

    // 5) output projection: out = attn @ proj_w^T + proj_b
    gemm2_kernel<<<dim3(C_ / 128, M / 128), 256, 0, stream>>>(
        flag, attn, pwb, pbb, d_out);
}